// Round 2
// baseline (160.157 us; speedup 1.0000x reference)
//
#include <hip/hip_runtime.h>
#include <hip/hip_bf16.h>
#include <math.h>

// Problem constants (from reference setup_inputs)
#define BS 4
#define C  3
#define D  8
#define K  10
#define K1 11
#define H  128
#define W  128
#define HW (H*W)

// Kernel 1: per-(b,d,k) heatmap normalization constant (separable sum).
__global__ void memb_norm_kernel(const float* __restrict__ kpd,
                                 float* __restrict__ norm) {
    int idx = blockIdx.x;              // 0 .. BS*D*K-1
    float kx = kpd[idx * 2 + 0];
    float ky = kpd[idx * 2 + 1];
    int lane = threadIdx.x;            // 0..63, one wave
    float sx = 0.f, sy = 0.f;
    #pragma unroll
    for (int j = lane; j < W; j += 64) {
        float coord = (float)j * (2.0f / 127.0f) - 1.0f;
        float ddx = coord - kx;
        float ddy = coord - ky;
        sx += __expf(-50.0f * ddx * ddx);
        sy += __expf(-50.0f * ddy * ddy);
    }
    #pragma unroll
    for (int o = 32; o > 0; o >>= 1) {
        sx += __shfl_down(sx, o, 64);
        sy += __shfl_down(sy, o, 64);
    }
    if (lane == 0) norm[idx] = 1.0f / (sx * sy);
}

// Kernel 2: one thread per 4 consecutive pixels of one (b,di,k) slice.
// Exploits: px steps by exactly 1.0 per pixel (align_corners, 128->64 grid
// scale), so all 4 pixels share bilinear weights; gathers collapse to
// 5 consecutive source columns x 2 rows x 3 channels; stores are float4.
__global__ void memb_main_kernel(const float* __restrict__ src,
                                 const float* __restrict__ kpd,
                                 const float* __restrict__ kps,
                                 const float* __restrict__ norm,
                                 float* __restrict__ out) {
    int t = blockIdx.x * blockDim.x + threadIdx.x;
    const int total = BS * D * K1 * (HW / 4);
    if (t >= total) return;

    int wi = (t & 31) << 2;          // 0,4,...,124
    int hi = (t >> 5) & (H - 1);
    int s  = t >> 12;                // slice: (b*D+di)*K1 + k
    int k  = s % K1;
    int r  = s / K1;                 // b*D + di
    int di = r & (D - 1);
    int b  = r >> 3;

    float xb = (float)wi * (2.0f / 127.0f) - 1.0f;
    float y  = (float)hi * (2.0f / 127.0f) - 1.0f;

    float heat0 = 0.f, heat1 = 0.f, heat2 = 0.f, heat3 = 0.f;
    float dxv = 0.f, dyv = 0.f;
    if (k > 0) {
        int kidx = r * K + (k - 1);
        float kx  = kpd[kidx * 2 + 0];
        float ky  = kpd[kidx * 2 + 1];
        dxv = kps[kidx * 2 + 0] - kx;
        dyv = kps[kidx * 2 + 1] - ky;
        float ey2 = (y - ky) * (y - ky);
        float nrm = norm[kidx];
        float e0 = xb - kx;
        float e1 = e0 + (2.0f / 127.0f);
        float e2 = e0 + (4.0f / 127.0f);
        float e3 = e0 + (6.0f / 127.0f);
        heat0 = __expf(-50.0f * (e0 * e0 + ey2)) * nrm;
        heat1 = __expf(-50.0f * (e1 * e1 + ey2)) * nrm;
        heat2 = __expf(-50.0f * (e2 * e2 + ey2)) * nrm;
        heat3 = __expf(-50.0f * (e3 * e3 + ey2)) * nrm;
    }

    // Bilinear setup (shared by the 4 pixels; px steps by exactly 1.0).
    float px = (xb + dxv + 1.0f) * 63.5f;
    float py = (y  + dyv + 1.0f) * 63.5f;
    float fx0 = floorf(px), fy0 = floorf(py);
    int x0 = (int)fx0, y0 = (int)fy0, y1 = y0 + 1;
    float wx1 = px - fx0, wx0 = 1.0f - wx1;
    float wy1 = py - fy0, wy0 = 1.0f - wy1;
    float vy0 = (y0 >= 0 && y0 <= H - 1) ? 1.0f : 0.0f;
    float vy1 = (y1 >= 0 && y1 <= H - 1) ? 1.0f : 0.0f;
    int cy0 = min(max(y0, 0), H - 1);
    int cy1 = min(max(y1, 0), H - 1);

    int   cc[5];
    float vc[5];
    #pragma unroll
    for (int j = 0; j < 5; j++) {
        int xc = x0 + j;
        vc[j] = (xc >= 0 && xc <= W - 1) ? 1.0f : 0.0f;
        cc[j] = min(max(xc, 0), W - 1);
    }

    const float* sb = src + (size_t)b * C * HW;
    float4 vout[C];
    #pragma unroll
    for (int ci = 0; ci < C; ci++) {
        const float* r0 = sb + ci * HW + cy0 * W;
        const float* r1 = sb + ci * HW + cy1 * W;
        float s0[5], s1[5];
        #pragma unroll
        for (int j = 0; j < 5; j++) {
            s0[j] = r0[cc[j]] * (vc[j] * vy0);
            s1[j] = r1[cc[j]] * (vc[j] * vy1);
        }
        float* vo = (float*)&vout[ci];
        #pragma unroll
        for (int i = 0; i < 4; i++) {
            vo[i] = wy0 * (wx0 * s0[i] + wx1 * s0[i + 1])
                  + wy1 * (wx0 * s1[i] + wx1 * s1[i + 1]);
        }
    }

    // out flat index: ((b*66 + k*6 + j)*D + di)*HW + hi*W + wi  (16B aligned)
    const size_t cs = (size_t)D * HW;
    size_t base = ((size_t)(b * 66 + k * 6) * D + di) * HW + hi * W + wi;
    *(float4*)(out + base)          = make_float4(heat0, heat1, heat2, heat3);
    *(float4*)(out + base + cs)     = make_float4(dxv, dxv, dxv, dxv);
    *(float4*)(out + base + 2 * cs) = make_float4(dyv, dyv, dyv, dyv);
    *(float4*)(out + base + 3 * cs) = vout[0];
    *(float4*)(out + base + 4 * cs) = vout[1];
    *(float4*)(out + base + 5 * cs) = vout[2];
}

extern "C" void kernel_launch(void* const* d_in, const int* in_sizes, int n_in,
                              void* d_out, int out_size, void* d_ws, size_t ws_size,
                              hipStream_t stream) {
    const float* src = (const float*)d_in[0];   // (4,3,1,128,128)
    const float* kpd = (const float*)d_in[1];   // (4,8,10,2)
    const float* kps = (const float*)d_in[2];   // (4,8,10,2)
    float* out  = (float*)d_out;                // (4,66,8,128,128)
    float* norm = (float*)d_ws;                 // 320 floats

    memb_norm_kernel<<<BS * D * K, 64, 0, stream>>>(kpd, norm);

    const int total = BS * D * K1 * (HW / 4);   // 1,441,792
    const int block = 256;
    const int grid = (total + block - 1) / block;
    memb_main_kernel<<<grid, block, 0, stream>>>(src, kpd, kps, norm, out);
}